// Round 19
// baseline (180.909 us; speedup 1.0000x reference)
//
#include <hip/hip_runtime.h>
#include <hip/hip_bf16.h>
#include <stdint.h>

// Problem constants (B=4, S=1024, D=1024, H=16, DK=64, DFF=2048)
#define TOK   4096
#define DMODEL 1024
#define DFF    2048
#define NHEAD  16
#define DK     64

typedef unsigned short u16;
typedef __attribute__((ext_vector_type(8))) short short8;   // 8 bf16 = 4 VGPR
typedef __attribute__((ext_vector_type(4))) float f32x4;

typedef __attribute__((address_space(1))) void gvoid;
typedef __attribute__((address_space(3))) void lvoid;

#define QSCALE   0.35355339f   // 8^-1/2 ; scores get x0.125 = QSCALE^2
#define QUNSCALE 2.82842712f   // undo V's extra QSCALE at attn output

__device__ __forceinline__ u16 f2b(float f) {               // fp32 -> bf16 RNE
    uint32_t x = __builtin_bit_cast(uint32_t, f);
    x += 0x7FFFu + ((x >> 16) & 1u);
    return (u16)(x >> 16);
}
__device__ __forceinline__ float b2f(u16 u) {
    uint32_t x = ((uint32_t)u) << 16;
    return __builtin_bit_cast(float, x);
}
// packed pair of bf16 (RNE), integer path (cold paths)
__device__ __forceinline__ uint32_t f2b2(float lo, float hi) {
    return (uint32_t)f2b(lo) | ((uint32_t)f2b(hi) << 16);
}
// packed pair of bf16 via HW v_cvt_pk_bf16_f32 (1 VALU op; RNE) — hot paths.
__device__ __forceinline__ uint32_t cvtpk(float lo, float hi) {
    uint32_t r;
    asm("v_cvt_pk_bf16_f32 %0, %1, %2" : "=v"(r) : "v"(lo), "v"(hi));
    return r;
}

// async global->LDS, 16B per lane. LDS dest = wave-uniform base + lane*16.
__device__ __forceinline__ void gload16(const void* g, void* l) {
    __builtin_amdgcn_global_load_lds((gvoid*)g, (lvoid*)l, 16, 0, 0);
}

// ---------------------------------------------------------------------------
// Weight transpose tile: W[K,N] fp32 -> Wt[N,K] bf16, one 64x64 tile.
// ---------------------------------------------------------------------------
__device__ __forceinline__ void cvt_tr_dev(
    const float* __restrict__ W, u16* __restrict__ Wt, int K, int N,
    int bx, int by, int tid, u16 (*T)[68])
{
    const int tx = tid & 15, ty = tid >> 4;
    const int n0 = bx * 64, k0 = by * 64;
#pragma unroll
    for (int i = 0; i < 4; i++) {
        int k = ty + i * 16;
        float4 v = *(const float4*)&W[(size_t)(k0 + k) * N + n0 + tx * 4];
        T[tx * 4 + 0][k] = f2b(v.x);
        T[tx * 4 + 1][k] = f2b(v.y);
        T[tx * 4 + 2][k] = f2b(v.z);
        T[tx * 4 + 3][k] = f2b(v.w);
    }
    __syncthreads();
#pragma unroll
    for (int i = 0; i < 4; i++) {
        int n = ty + i * 16;
        ushort4 o;
        o.x = T[n][tx * 4 + 0]; o.y = T[n][tx * 4 + 1];
        o.z = T[n][tx * 4 + 2]; o.w = T[n][tx * 4 + 3];
        *(ushort4*)&Wt[(size_t)(n0 + n) * K + k0 + tx * 4] = o;
    }
}

// ---------------------------------------------------------------------------
// prep1: Wq transpose (256 blocks) + x convert (1024 blocks).
// ---------------------------------------------------------------------------
__global__ __launch_bounds__(256) void prep1(
    const float* __restrict__ Wq, u16* __restrict__ Wqt,
    const float* __restrict__ x, u16* __restrict__ xb)
{
    __shared__ u16 T[64][68];
    const int id = blockIdx.x, tid = threadIdx.x;
    if (id < 256) {
        cvt_tr_dev(Wq, Wqt, 1024, 1024, id & 15, id >> 4, tid, T);
    } else {
        size_t base = (size_t)(id - 256) * 1024 + tid;   // float4 units
#pragma unroll
        for (int j = 0; j < 4; j++) {
            float4 v = ((const float4*)x)[base + j * 256];
            ((uint2*)xb)[base + j * 256] =
                make_uint2(f2b2(v.x, v.y), f2b2(v.z, v.w));
        }
    }
}

// ---------------------------------------------------------------------------
// PER-WAVE bf16 MFMA GEMM, 3-DEEP self-paced pipeline. Block = 1 wave owning
// a 64x64 C-tile; private LDS 48 KB (3 bufs x (A 8KB + B 8KB)); no barriers.
// Steady state: wait vmcnt(32) for tile t+1 (issued 2 iterations earlier,
// ~700cy cover) while t+2/t+3's 32 loads stay in flight. WAR on buffer reuse
// closed by lgkmcnt(0) before re-staging. Tail: vmcnt(16) then vmcnt(0).
// Per K-step: 32 MFMA (16x16x32), 16 ds_read_b128, 16 gload16.
// XCD-chunked 1-D grid.
// ---------------------------------------------------------------------------
template<bool RELU, bool OUTBF16, bool QOUT>
__global__ __launch_bounds__(64) void gemm_w(
    const u16* __restrict__ A, const u16* __restrict__ Bt,
    const float* __restrict__ bias, void* __restrict__ Cv,
    u16* __restrict__ CT, float oscale,
    int M, int N, int K)
{
    __shared__ __align__(16) u16 As[3 * 4096];   // 24 KB
    __shared__ __align__(16) u16 Bs[3 * 4096];   // 24 KB

    const int lane = threadIdx.x;                // 0..63
    const int frow = lane & 15, fk = lane >> 4;

    const int gx = N >> 6;
    const int gy = M >> 6;
    const int rpx = gy >> 3;                     // row-tiles per XCD
    const int L = blockIdx.x;
    const int xcd = L & 7, within = L >> 3;
    const int yy = xcd * rpx + within / gx;
    const int xx = within % gx;

    const int row0 = yy * 64;
    const int col0 = xx * 64;

    // staging: inst covers rows [inst*8, inst*8+8); lane -> (r = s>>3, c = s&7)
    // global chunk kc = (c ^ (r&7))*8  [inverse-swizzled source]
    const u16* gA[8]; const u16* gB[8];
#pragma unroll
    for (int inst = 0; inst < 8; inst++) {
        int s = inst * 64 + lane;
        int r = s >> 3;
        int kc = ((s & 7) ^ (r & 7)) * 8;
        gA[inst] = A  + (size_t)(row0 + r) * K + kc;
        gB[inst] = Bt + (size_t)(col0 + r) * K + kc;
    }

    // fragment read offsets (swizzled): row r, k-chunk slot (kk*4+fk)^(r&7)
    int aoff[4][2];
#pragma unroll
    for (int m = 0; m < 4; m++) {
        int r = m * 16 + frow;
#pragma unroll
        for (int kk = 0; kk < 2; kk++)
            aoff[m][kk] = r * 64 + (((kk << 2) + fk) ^ (r & 7)) * 8;
    }

    f32x4 acc[4][4] = {};
    const int nT = K >> 6;     // 16 or 32 (>= 4)

    // prologue: stage tiles 0,1,2 (16 loads each); wait tile 0 only
#pragma unroll
    for (int d = 0; d < 3; d++)
#pragma unroll
        for (int inst = 0; inst < 8; inst++) {
            gload16(gA[inst] + d * 64, As + d * 4096 + inst * 512);
            gload16(gB[inst] + d * 64, Bs + d * 4096 + inst * 512);
        }
    asm volatile("s_waitcnt vmcnt(32)" ::: "memory");
    __builtin_amdgcn_sched_barrier(0);

    int cur = 0;
    for (int t = 0; t < nT; t++) {
        const u16* Ab = As + cur * 4096;
        const u16* Bb = Bs + cur * 4096;

        // ds_read all fragments of tile t into registers
        short8 a[4][2], b[4][2];
#pragma unroll
        for (int m = 0; m < 4; m++)
#pragma unroll
            for (int kk = 0; kk < 2; kk++) {
                a[m][kk] = *(const short8*)(Ab + aoff[m][kk]);
                b[m][kk] = *(const short8*)(Bb + aoff[m][kk]);
            }

        // all ds_reads executed -> safe to overwrite buf cur with tile t+3
        asm volatile("s_waitcnt lgkmcnt(0)" ::: "memory");
        __builtin_amdgcn_sched_barrier(0);
        if (t + 3 < nT) {
            const int k0 = (t + 3) << 6;
#pragma unroll
            for (int inst = 0; inst < 8; inst++) {
                gload16(gA[inst] + k0, As + cur * 4096 + inst * 512);
                gload16(gB[inst] + k0, Bs + cur * 4096 + inst * 512);
            }
        }

        // compute (covers in-flight staging latency)
#pragma unroll
        for (int m = 0; m < 4; m++)
#pragma unroll
            for (int n = 0; n < 4; n++)
#pragma unroll
                for (int kk = 0; kk < 2; kk++)
                    acc[m][n] = __builtin_amdgcn_mfma_f32_16x16x32_bf16(
                        a[m][kk], b[n][kk], acc[m][n], 0, 0, 0);

        // wait tile t+1 ready (keep newer tiles' loads in flight)
        if (t + 1 < nT) {
            if (t + 3 < nT)      asm volatile("s_waitcnt vmcnt(32)" ::: "memory");
            else if (t + 2 < nT) asm volatile("s_waitcnt vmcnt(16)" ::: "memory");
            else                 asm volatile("s_waitcnt vmcnt(0)"  ::: "memory");
            __builtin_amdgcn_sched_barrier(0);
        }
        cur = (cur == 2) ? 0 : cur + 1;
    }

    // epilogue: C/D layout col=lane&15, row=(lane>>4)*4+i
#pragma unroll
    for (int n = 0; n < 4; n++) {
        const int gcol = col0 + n * 16 + frow;
        const float bv = bias[gcol];
#pragma unroll
        for (int m = 0; m < 4; m++) {
            const int grow0 = row0 + m * 16 + fk * 4;
            float v[4];
#pragma unroll
            for (int i = 0; i < 4; i++) {
                v[i] = (acc[m][n][i] + bv) * oscale;
                if (RELU) v[i] = fmaxf(v[i], 0.0f);
                if (OUTBF16)
                    ((u16*)Cv)[(size_t)(grow0 + i) * N + gcol] = f2b(v[i]);
                else
                    ((float*)Cv)[(size_t)(grow0 + i) * N + gcol] = v[i];
            }
            if (QOUT) {
                const int hh = gcol >> 6, d = gcol & 63;
                const int bb = grow0 >> 10, sl = grow0 & 1023;
                *(uint2*)&CT[(((size_t)(bb * 16 + hh) * 64 + d) << 10) + sl] =
                    make_uint2(f2b2(v[0], v[1]), f2b2(v[2], v[3]));
            }
        }
    }
}

// ---------------------------------------------------------------------------
// bf16 MFMA flash attention (r15 structure, best measured) + piggy-backed
// Wo/W1/W2 transposes as blocks 512..1791. P-pack via v_cvt_pk_bf16_f32.
// ---------------------------------------------------------------------------
__global__ __launch_bounds__(256, 2) void attn_prepw(
    const u16* __restrict__ qb, const u16* __restrict__ qT,
    u16* __restrict__ zb,
    const float* __restrict__ Wo, const float* __restrict__ W1,
    const float* __restrict__ W2,
    u16* __restrict__ Wot, u16* __restrict__ W1t, u16* __restrict__ W2t)
{
    __shared__ __align__(16) u16 Ks[2][64 * 64];   // [kv][dk], 2 x 8 KB
    __shared__ __align__(16) u16 Kt[2][64 * 64];   // [dk][kv], 2 x 8 KB
    __shared__ __align__(16) u16 Ps[128 * 64];     // [q][kv], 16 KB

    const int tid = threadIdx.x;
    const int id  = blockIdx.x;

    if (id >= 512) {               // weight-transpose blocks
        u16 (*T)[68] = reinterpret_cast<u16 (*)[68]>(&Ks[0][0]);
        int t = id - 512;
        if (t < 256)       cvt_tr_dev(Wo, Wot, 1024, 1024, t & 15, t >> 4, tid, T);
        else if (t < 768)  { t -= 256; cvt_tr_dev(W1, W1t, 1024, 2048, t & 31, t >> 5, tid, T); }
        else               { t -= 768; cvt_tr_dev(W2, W2t, 2048, 1024, t & 15, t >> 4, tid, T); }
        return;
    }

    const int lane = tid & 63;
    const int w    = tid >> 6;
    const int frow = lane & 15, fk = lane >> 4;

    const int h  = id & 15;
    const int qt = (id >> 4) & 7;
    const int b  = id >> 7;
    const int q0 = qt * 128;

    const u16* qhead = qb + ((size_t)b * 1024) * 1024 + h * 64;  // + s*1024 + d
    const u16* thead = qT + ((size_t)(b * 16 + h) * 64) * 1024;  // + d*1024 + s

    // stage kv-tile 0 into buffer 0 (swizzled rows, wave-uniform dest)
#pragma unroll
    for (int inst = 0; inst < 2; inst++) {
        int s = inst * 256 + tid, r = s >> 3, kc = ((s & 7) ^ (r & 7)) * 8;
        gload16(qhead + (size_t)r * 1024 + kc, Ks[0] + inst * 2048 + w * 512);
        gload16(thead + (size_t)r * 1024 + kc, Kt[0] + inst * 2048 + w * 512);
    }

    // Q fragments straight from global (read once, stays in registers)
    short8 qf[2][2];
#pragma unroll
    for (int m = 0; m < 2; m++) {
        int r = q0 + w * 32 + m * 16 + frow;
#pragma unroll
        for (int kk = 0; kk < 2; kk++)
            qf[m][kk] = *(const short8*)(qhead + (size_t)r * 1024 + kk * 32 + fk * 8);
    }

    float lp[2] = {};     // per-lane partial row-sum for q = w*32+mq*16+frow
    f32x4 o[2][4] = {};

    __syncthreads();   // tile-0 staging complete

    for (int t = 0; t < 16; t++) {
        const int cur = t & 1;
        if (t < 15) {   // prefetch next kv tile into the other buffer
            const int kv = (t + 1) * 64;
#pragma unroll
            for (int inst = 0; inst < 2; inst++) {
                int s = inst * 256 + tid, r = s >> 3, kc = ((s & 7) ^ (r & 7)) * 8;
                gload16(qhead + (size_t)(kv + r) * 1024 + kc,
                        Ks[cur ^ 1] + inst * 2048 + w * 512);
                gload16(thead + (size_t)r * 1024 + kv + kc,
                        Kt[cur ^ 1] + inst * 2048 + w * 512);
            }
        }

        // ---- S^T = K Q^T (swapped operands; scores pre-scaled by 0.125)
        short8 kf[4][2];
#pragma unroll
        for (int n = 0; n < 4; n++) {
            int r = n * 16 + frow;
#pragma unroll
            for (int kk = 0; kk < 2; kk++)
                kf[n][kk] = *(const short8*)(Ks[cur] + r * 64 +
                                             (((kk << 2) + fk) ^ (r & 7)) * 8);
        }
        f32x4 st[4][2] = {};   // st[nk][mq]: rows kv, cols q
        __builtin_amdgcn_s_setprio(1);
#pragma unroll
        for (int nk = 0; nk < 4; nk++)
#pragma unroll
            for (int mq = 0; mq < 2; mq++)
#pragma unroll
                for (int kk = 0; kk < 2; kk++)
                    st[nk][mq] = __builtin_amdgcn_mfma_f32_16x16x32_bf16(
                        kf[nk][kk], qf[mq][kk], st[nk][mq], 0, 0, 0);
        __builtin_amdgcn_s_setprio(0);

        // ---- P = exp(S); lane holds P[kv = nk*16+fk*4+i][q = mq*16+frow]:
        //      kv-contiguous -> v_cvt_pk_bf16_f32 pairs + b64 LDS writes
#pragma unroll
        for (int mq = 0; mq < 2; mq++) {
            const int r = w * 32 + mq * 16 + frow;
            const int rb = r * 64, sw = (r & 7) << 3;
#pragma unroll
            for (int nk = 0; nk < 4; nk++) {
                float p0 = __expf(st[nk][mq][0]);
                float p1 = __expf(st[nk][mq][1]);
                float p2 = __expf(st[nk][mq][2]);
                float p3 = __expf(st[nk][mq][3]);
                lp[mq] += (p0 + p1) + (p2 + p3);
                *(uint2*)&Ps[rb + ((nk * 16 + fk * 4) ^ sw)] =
                    make_uint2(cvtpk(p0, p1), cvtpk(p2, p3));
            }
        }

        // ---- O += P V   (P rows written above by this same wave)
        short8 pa[2][2], vf[4][2];
#pragma unroll
        for (int m = 0; m < 2; m++) {
            int r = w * 32 + m * 16 + frow;
#pragma unroll
            for (int kk = 0; kk < 2; kk++)
                pa[m][kk] = *(const short8*)(Ps + r * 64 +
                                             (((kk << 2) + fk) ^ (r & 7)) * 8);
        }
#pragma unroll
        for (int n = 0; n < 4; n++) {
            int r = n * 16 + frow;
#pragma unroll
            for (int kk = 0; kk < 2; kk++)
                vf[n][kk] = *(const short8*)(Kt[cur] + r * 64 +
                                             (((kk << 2) + fk) ^ (r & 7)) * 8);
        }
        __builtin_amdgcn_s_setprio(1);
#pragma unroll
        for (int m = 0; m < 2; m++)
#pragma unroll
            for (int n = 0; n < 4; n++)
#pragma unroll
                for (int kk = 0; kk < 2; kk++)
                    o[m][n] = __builtin_amdgcn_mfma_f32_16x16x32_bf16(
                        pa[m][kk], vf[n][kk], o[m][n], 0, 0, 0);
        __builtin_amdgcn_s_setprio(0);

        __syncthreads();   // staging(t+1) drained; all waves done with buf cur
    }

    // ---- epilogue: finish row-sums, redistribute, write z = O*QUNSCALE/l
#pragma unroll
    for (int mq = 0; mq < 2; mq++) {
        lp[mq] += __shfl_xor(lp[mq], 16);
        lp[mq] += __shfl_xor(lp[mq], 32);
    }
#pragma unroll
    for (int m = 0; m < 2; m++)
#pragma unroll
        for (int i = 0; i < 4; i++) {
            const float lfull = __shfl(lp[m], fk * 4 + i);  // lane frow=fk*4+i
            const float rl = QUNSCALE / lfull;
            const size_t gr = (size_t)(b * 1024 + q0 + w * 32 + m * 16 + fk * 4 + i);
#pragma unroll
            for (int n = 0; n < 4; n++)
                zb[gr * 1024 + h * 64 + n * 16 + frow] = f2b(o[m][n][i] * rl);
        }
}

// ---------------------------------------------------------------------------
// Fused residual add + LayerNorm (ddof=1, eps on std). Vectorized (G13).
// ---------------------------------------------------------------------------
__device__ __forceinline__ float4 ld4(const float* p) { return *(const float4*)p; }
__device__ __forceinline__ float4 ld4(const u16* p) {
    ushort4 u = *(const ushort4*)p;
    return make_float4(b2f(u.x), b2f(u.y), b2f(u.z), b2f(u.w));
}
__device__ __forceinline__ void st4(float* p, float4 v) { *(float4*)p = v; }
__device__ __forceinline__ void st4(u16* p, float4 v) {
    *(uint2*)p = make_uint2(f2b2(v.x, v.y), f2b2(v.z, v.w));
}

template<typename TA, typename TB, typename TO>
__global__ __launch_bounds__(256) void add_ln(
    const TA* __restrict__ a, const TB* __restrict__ b,
    const float* __restrict__ alpha, const float* __restrict__ beta,
    TO* __restrict__ out)
{
    const int row = blockIdx.x;
    const int c = threadIdx.x * 4;
    float4 va = ld4(a + (size_t)row * DMODEL + c);
    float4 vb = ld4(b + (size_t)row * DMODEL + c);
    float v0 = va.x + vb.x, v1 = va.y + vb.y;
    float v2 = va.z + vb.z, v3 = va.w + vb.w;

    float sum = (v0 + v1) + (v2 + v3);
    float sq  = (v0 * v0 + v1 * v1) + (v2 * v2 + v3 * v3);
#pragma unroll
    for (int off = 32; off > 0; off >>= 1) {
        sum += __shfl_xor(sum, off);
        sq  += __shfl_xor(sq, off);
    }
    __shared__ float s1[4], s2[4];
    const int wid = threadIdx.x >> 6, lane = threadIdx.x & 63;
    if (lane == 0) { s1[wid] = sum; s2[wid] = sq; }
    __syncthreads();
    sum = (s1[0] + s1[1]) + (s1[2] + s1[3]);
    sq  = (s2[0] + s2[1]) + (s2[2] + s2[3]);

    const float mean = sum * (1.0f / 1024.0f);
    float var = (sq - 1024.0f * mean * mean) * (1.0f / 1023.0f);
    var = fmaxf(var, 0.0f);
    const float rdenom = 1.0f / (sqrtf(var) + 1e-6f);

    float4 al = *(const float4*)(alpha + c);
    float4 be = *(const float4*)(beta + c);
    float4 r;
    r.x = al.x * (v0 - mean) * rdenom + be.x;
    r.y = al.y * (v1 - mean) * rdenom + be.y;
    r.z = al.z * (v2 - mean) * rdenom + be.z;
    r.w = al.w * (v3 - mean) * rdenom + be.w;
    st4(out + (size_t)row * DMODEL + c, r);
}

// ---------------------------------------------------------------------------
extern "C" void kernel_launch(void* const* d_in, const int* in_sizes, int n_in,
                              void* d_out, int out_size, void* d_ws, size_t ws_size,
                              hipStream_t stream) {
    const float* x     = (const float*)d_in[0];
    const float* Wq    = (const float*)d_in[1];
    const float* bq    = (const float*)d_in[2];
    const float* Wo    = (const float*)d_in[3];
    const float* bo    = (const float*)d_in[4];
    const float* W1    = (const float*)d_in[5];
    const float* b1    = (const float*)d_in[6];
    const float* W2    = (const float*)d_in[7];
    const float* b2    = (const float*)d_in[8];
    const float* alpha = (const float*)d_in[9];
    const float* beta  = (const float*)d_in[10];

    // workspace layout (liveness-based reuse; 52 MB)
    char* base = (char*)d_ws;
    u16* Wqt = (u16*)base;                       //  0M: 2 MB
    u16* Wot = (u16*)(base + (2u  << 20));       //  2M: 2 MB
    u16* W1t = (u16*)(base + (4u  << 20));       //  4M: 4 MB
    u16* W2t = (u16*)(base + (8u  << 20));       //  8M: 4 MB
    u16* zb  = (u16*)(base + (12u << 20));       // 12M: 8 MB (attn out)
    u16* x1b = zb;                               //      reuse after Wo-gemm
    u16* qb  = (u16*)(base + (20u << 20));       // 20M: 8 MB (dead after attn)
    u16* g2  = qb;                               //      bf16 8 MB (FF2 out)
    u16* qT  = (u16*)(base + (28u << 20));       // 28M: 8 MB (dead after attn)
    u16* g   = qT;                               //      bf16 8 MB (Wo out)
    u16* xb  = (u16*)(base + (36u << 20));       // 36M: 8 MB (live thru LN1)
    u16* hb  = (u16*)(base + (36u << 20));       // 36M: 16 MB (xb dead pre-FF1)

    dim3 blk(256);
    dim3 wblk(64);

    // prep1: Wq transpose + x convert
    prep1<<<dim3(1280), blk, 0, stream>>>(Wq, Wqt, x, xb);

    // q = (x @ Wq + bq) * 8^-1/2, dual layout (qb row-major, qT transposed)
    gemm_w<false, true, true><<<dim3(1024), wblk, 0, stream>>>(
        xb, Wqt, bq, qb, qT, QSCALE, TOK, 1024, 1024);
    // attention -> zb + Wo/W1/W2 transposes (concurrent independent blocks)
    attn_prepw<<<dim3(1792), blk, 0, stream>>>(
        qb, qT, zb, Wo, W1, W2, Wot, W1t, W2t);
    // g = z @ Wo + bo  (bf16; writes over qT which is now dead)
    gemm_w<false, true, false><<<dim3(1024), wblk, 0, stream>>>(
        zb, Wot, bo, g, nullptr, 1.0f, TOK, 1024, 1024);
    // x1b = LN(xb + g)  (bf16 residual)
    add_ln<u16, u16, u16><<<dim3(TOK), blk, 0, stream>>>(xb, g, alpha, beta, x1b);
    // hb = relu(x1 @ W1 + b1)  (bf16)
    gemm_w<true, true, false><<<dim3(2048), wblk, 0, stream>>>(
        x1b, W1t, b1, hb, nullptr, 1.0f, TOK, 2048, 1024);
    // g2 = h @ W2 + b2  (bf16)
    gemm_w<false, true, false><<<dim3(1024), wblk, 0, stream>>>(
        hb, W2t, b2, g2, nullptr, 1.0f, TOK, 1024, 2048);
    // out = LN(x1 + g2)
    add_ln<u16, u16, float><<<dim3(TOK), blk, 0, stream>>>(
        x1b, g2, alpha, beta, (float*)d_out);
}

// Round 20
// 137.524 us; speedup vs baseline: 1.3155x; 1.3155x over previous
//
#include <hip/hip_runtime.h>
#include <hip/hip_bf16.h>
#include <stdint.h>

// Problem constants (B=4, S=1024, D=1024, H=16, DK=64, DFF=2048)
#define TOK   4096
#define DMODEL 1024
#define DFF    2048
#define NHEAD  16
#define DK     64

typedef unsigned short u16;
typedef __attribute__((ext_vector_type(8))) short short8;   // 8 bf16 = 4 VGPR
typedef __attribute__((ext_vector_type(4))) float f32x4;

typedef __attribute__((address_space(1))) void gvoid;
typedef __attribute__((address_space(3))) void lvoid;

#define QSCALE   0.35355339f   // 8^-1/2 ; scores get x0.125 = QSCALE^2
#define QUNSCALE 2.82842712f   // undo V's extra QSCALE at attn output

__device__ __forceinline__ u16 f2b(float f) {               // fp32 -> bf16 RNE
    uint32_t x = __builtin_bit_cast(uint32_t, f);
    x += 0x7FFFu + ((x >> 16) & 1u);
    return (u16)(x >> 16);
}
__device__ __forceinline__ float b2f(u16 u) {
    uint32_t x = ((uint32_t)u) << 16;
    return __builtin_bit_cast(float, x);
}
// packed pair of bf16 (RNE), integer path (cold paths)
__device__ __forceinline__ uint32_t f2b2(float lo, float hi) {
    return (uint32_t)f2b(lo) | ((uint32_t)f2b(hi) << 16);
}
// packed pair of bf16 via HW v_cvt_pk_bf16_f32 (1 VALU op; RNE) — hot paths.
__device__ __forceinline__ uint32_t cvtpk(float lo, float hi) {
    uint32_t r;
    asm("v_cvt_pk_bf16_f32 %0, %1, %2" : "=v"(r) : "v"(lo), "v"(hi));
    return r;
}

// async global->LDS, 16B per lane. LDS dest = wave-uniform base + lane*16.
__device__ __forceinline__ void gload16(const void* g, void* l) {
    __builtin_amdgcn_global_load_lds((gvoid*)g, (lvoid*)l, 16, 0, 0);
}

// ---------------------------------------------------------------------------
// Weight transpose tile: W[K,N] fp32 -> Wt[N,K] bf16, one 64x64 tile.
// ---------------------------------------------------------------------------
__device__ __forceinline__ void cvt_tr_dev(
    const float* __restrict__ W, u16* __restrict__ Wt, int K, int N,
    int bx, int by, int tid, u16 (*T)[68])
{
    const int tx = tid & 15, ty = tid >> 4;
    const int n0 = bx * 64, k0 = by * 64;
#pragma unroll
    for (int i = 0; i < 4; i++) {
        int k = ty + i * 16;
        float4 v = *(const float4*)&W[(size_t)(k0 + k) * N + n0 + tx * 4];
        T[tx * 4 + 0][k] = f2b(v.x);
        T[tx * 4 + 1][k] = f2b(v.y);
        T[tx * 4 + 2][k] = f2b(v.z);
        T[tx * 4 + 3][k] = f2b(v.w);
    }
    __syncthreads();
#pragma unroll
    for (int i = 0; i < 4; i++) {
        int n = ty + i * 16;
        ushort4 o;
        o.x = T[n][tx * 4 + 0]; o.y = T[n][tx * 4 + 1];
        o.z = T[n][tx * 4 + 2]; o.w = T[n][tx * 4 + 3];
        *(ushort4*)&Wt[(size_t)(n0 + n) * K + k0 + tx * 4] = o;
    }
}

// ---------------------------------------------------------------------------
// prep1: Wq transpose (256 blocks) + x convert (1024 blocks).
// ---------------------------------------------------------------------------
__global__ __launch_bounds__(256) void prep1(
    const float* __restrict__ Wq, u16* __restrict__ Wqt,
    const float* __restrict__ x, u16* __restrict__ xb)
{
    __shared__ u16 T[64][68];
    const int id = blockIdx.x, tid = threadIdx.x;
    if (id < 256) {
        cvt_tr_dev(Wq, Wqt, 1024, 1024, id & 15, id >> 4, tid, T);
    } else {
        size_t base = (size_t)(id - 256) * 1024 + tid;   // float4 units
#pragma unroll
        for (int j = 0; j < 4; j++) {
            float4 v = ((const float4*)x)[base + j * 256];
            ((uint2*)xb)[base + j * 256] =
                make_uint2(f2b2(v.x, v.y), f2b2(v.z, v.w));
        }
    }
}

// ---------------------------------------------------------------------------
// PER-WAVE bf16 MFMA GEMM: block = 1 wave (64 threads) owning a 64x64 C-tile.
// No __syncthreads anywhere: the wave stages its OWN A/B panels into private
// LDS (32 KB -> 5 blocks/CU) via global_load_lds, self-paced with counted
// s_waitcnt vmcnt(16) (2-deep prefetch; never drains mid-loop). WAR on buffer
// reuse closed by lgkmcnt(0) before re-staging. (3-deep/48KB measured WORSE:
// occupancy 5->3 blocks/CU dominates the extra latency cover — r19.)
// Per K-step: 32 MFMA (16x16x32), 16 ds_read_b128, 16 gload16.
// XCD-chunked 1-D grid.
// ---------------------------------------------------------------------------
template<bool RELU, bool OUTBF16, bool QOUT>
__global__ __launch_bounds__(64) void gemm_w(
    const u16* __restrict__ A, const u16* __restrict__ Bt,
    const float* __restrict__ bias, void* __restrict__ Cv,
    u16* __restrict__ CT, float oscale,
    int M, int N, int K)
{
    __shared__ __align__(16) u16 As[2 * 4096];   // 16 KB
    __shared__ __align__(16) u16 Bs[2 * 4096];   // 16 KB

    const int lane = threadIdx.x;                // 0..63
    const int frow = lane & 15, fk = lane >> 4;

    const int gx = N >> 6;
    const int gy = M >> 6;
    const int rpx = gy >> 3;                     // row-tiles per XCD
    const int L = blockIdx.x;
    const int xcd = L & 7, within = L >> 3;
    const int yy = xcd * rpx + within / gx;
    const int xx = within % gx;

    const int row0 = yy * 64;
    const int col0 = xx * 64;

    // staging: inst covers rows [inst*8, inst*8+8); lane -> (r = s>>3, c = s&7)
    // global chunk kc = (c ^ (r&7))*8  [inverse-swizzled source]
    const u16* gA[8]; const u16* gB[8];
#pragma unroll
    for (int inst = 0; inst < 8; inst++) {
        int s = inst * 64 + lane;
        int r = s >> 3;
        int kc = ((s & 7) ^ (r & 7)) * 8;
        gA[inst] = A  + (size_t)(row0 + r) * K + kc;
        gB[inst] = Bt + (size_t)(col0 + r) * K + kc;
    }

    // fragment read offsets (swizzled): row r, k-chunk slot (kk*4+fk)^(r&7)
    int aoff[4][2];
#pragma unroll
    for (int m = 0; m < 4; m++) {
        int r = m * 16 + frow;
#pragma unroll
        for (int kk = 0; kk < 2; kk++)
            aoff[m][kk] = r * 64 + (((kk << 2) + fk) ^ (r & 7)) * 8;
    }

    f32x4 acc[4][4] = {};
    const int nT = K >> 6;     // 16 or 32

    // prologue: stage tiles 0 and 1 (16 loads each); wait tile 0 only
#pragma unroll
    for (int inst = 0; inst < 8; inst++) {
        gload16(gA[inst], As + inst * 512);
        gload16(gB[inst], Bs + inst * 512);
    }
#pragma unroll
    for (int inst = 0; inst < 8; inst++) {
        gload16(gA[inst] + 64, As + 4096 + inst * 512);
        gload16(gB[inst] + 64, Bs + 4096 + inst * 512);
    }
    asm volatile("s_waitcnt vmcnt(16)" ::: "memory");
    __builtin_amdgcn_sched_barrier(0);

    for (int t = 0; t < nT; t++) {
        const int cur = t & 1;
        const u16* Ab = As + cur * 4096;
        const u16* Bb = Bs + cur * 4096;

        // ds_read all fragments of tile t into registers
        short8 a[4][2], b[4][2];
#pragma unroll
        for (int m = 0; m < 4; m++)
#pragma unroll
            for (int kk = 0; kk < 2; kk++) {
                a[m][kk] = *(const short8*)(Ab + aoff[m][kk]);
                b[m][kk] = *(const short8*)(Bb + aoff[m][kk]);
            }

        // all ds_reads executed -> safe to overwrite buf cur with tile t+2
        asm volatile("s_waitcnt lgkmcnt(0)" ::: "memory");
        __builtin_amdgcn_sched_barrier(0);
        if (t + 2 < nT) {
            const int k0 = (t + 2) << 6;
#pragma unroll
            for (int inst = 0; inst < 8; inst++) {
                gload16(gA[inst] + k0, As + cur * 4096 + inst * 512);
                gload16(gB[inst] + k0, Bs + cur * 4096 + inst * 512);
            }
        }

        // compute (covers the in-flight staging latency)
#pragma unroll
        for (int m = 0; m < 4; m++)
#pragma unroll
            for (int n = 0; n < 4; n++)
#pragma unroll
                for (int kk = 0; kk < 2; kk++)
                    acc[m][n] = __builtin_amdgcn_mfma_f32_16x16x32_bf16(
                        a[m][kk], b[n][kk], acc[m][n], 0, 0, 0);

        // wait for tile t+1 (keep tile t+2's 16 loads in flight)
        if (t + 1 < nT) {
            if (t + 2 < nT) asm volatile("s_waitcnt vmcnt(16)" ::: "memory");
            else            asm volatile("s_waitcnt vmcnt(0)"  ::: "memory");
            __builtin_amdgcn_sched_barrier(0);
        }
    }

    // epilogue: C/D layout col=lane&15, row=(lane>>4)*4+i
#pragma unroll
    for (int n = 0; n < 4; n++) {
        const int gcol = col0 + n * 16 + frow;
        const float bv = bias[gcol];
#pragma unroll
        for (int m = 0; m < 4; m++) {
            const int grow0 = row0 + m * 16 + fk * 4;
            float v[4];
#pragma unroll
            for (int i = 0; i < 4; i++) {
                v[i] = (acc[m][n][i] + bv) * oscale;
                if (RELU) v[i] = fmaxf(v[i], 0.0f);
                if (OUTBF16)
                    ((u16*)Cv)[(size_t)(grow0 + i) * N + gcol] = f2b(v[i]);
                else
                    ((float*)Cv)[(size_t)(grow0 + i) * N + gcol] = v[i];
            }
            if (QOUT) {
                const int hh = gcol >> 6, d = gcol & 63;
                const int bb = grow0 >> 10, sl = grow0 & 1023;
                *(uint2*)&CT[(((size_t)(bb * 16 + hh) * 64 + d) << 10) + sl] =
                    make_uint2(f2b2(v[0], v[1]), f2b2(v[2], v[3]));
            }
        }
    }
}

// ---------------------------------------------------------------------------
// bf16 MFMA flash attention (r15 structure, best measured) + piggy-backed
// Wo/W1/W2 transposes as blocks 512..1791. P-pack via v_cvt_pk_bf16_f32.
// ---------------------------------------------------------------------------
__global__ __launch_bounds__(256, 2) void attn_prepw(
    const u16* __restrict__ qb, const u16* __restrict__ qT,
    u16* __restrict__ zb,
    const float* __restrict__ Wo, const float* __restrict__ W1,
    const float* __restrict__ W2,
    u16* __restrict__ Wot, u16* __restrict__ W1t, u16* __restrict__ W2t)
{
    __shared__ __align__(16) u16 Ks[2][64 * 64];   // [kv][dk], 2 x 8 KB
    __shared__ __align__(16) u16 Kt[2][64 * 64];   // [dk][kv], 2 x 8 KB
    __shared__ __align__(16) u16 Ps[128 * 64];     // [q][kv], 16 KB

    const int tid = threadIdx.x;
    const int id  = blockIdx.x;

    if (id >= 512) {               // weight-transpose blocks
        u16 (*T)[68] = reinterpret_cast<u16 (*)[68]>(&Ks[0][0]);
        int t = id - 512;
        if (t < 256)       cvt_tr_dev(Wo, Wot, 1024, 1024, t & 15, t >> 4, tid, T);
        else if (t < 768)  { t -= 256; cvt_tr_dev(W1, W1t, 1024, 2048, t & 31, t >> 5, tid, T); }
        else               { t -= 768; cvt_tr_dev(W2, W2t, 2048, 1024, t & 15, t >> 4, tid, T); }
        return;
    }

    const int lane = tid & 63;
    const int w    = tid >> 6;
    const int frow = lane & 15, fk = lane >> 4;

    const int h  = id & 15;
    const int qt = (id >> 4) & 7;
    const int b  = id >> 7;
    const int q0 = qt * 128;

    const u16* qhead = qb + ((size_t)b * 1024) * 1024 + h * 64;  // + s*1024 + d
    const u16* thead = qT + ((size_t)(b * 16 + h) * 64) * 1024;  // + d*1024 + s

    // stage kv-tile 0 into buffer 0 (swizzled rows, wave-uniform dest)
#pragma unroll
    for (int inst = 0; inst < 2; inst++) {
        int s = inst * 256 + tid, r = s >> 3, kc = ((s & 7) ^ (r & 7)) * 8;
        gload16(qhead + (size_t)r * 1024 + kc, Ks[0] + inst * 2048 + w * 512);
        gload16(thead + (size_t)r * 1024 + kc, Kt[0] + inst * 2048 + w * 512);
    }

    // Q fragments straight from global (read once, stays in registers)
    short8 qf[2][2];
#pragma unroll
    for (int m = 0; m < 2; m++) {
        int r = q0 + w * 32 + m * 16 + frow;
#pragma unroll
        for (int kk = 0; kk < 2; kk++)
            qf[m][kk] = *(const short8*)(qhead + (size_t)r * 1024 + kk * 32 + fk * 8);
    }

    float lp[2] = {};     // per-lane partial row-sum for q = w*32+mq*16+frow
    f32x4 o[2][4] = {};

    __syncthreads();   // tile-0 staging complete

    for (int t = 0; t < 16; t++) {
        const int cur = t & 1;
        if (t < 15) {   // prefetch next kv tile into the other buffer
            const int kv = (t + 1) * 64;
#pragma unroll
            for (int inst = 0; inst < 2; inst++) {
                int s = inst * 256 + tid, r = s >> 3, kc = ((s & 7) ^ (r & 7)) * 8;
                gload16(qhead + (size_t)(kv + r) * 1024 + kc,
                        Ks[cur ^ 1] + inst * 2048 + w * 512);
                gload16(thead + (size_t)r * 1024 + kv + kc,
                        Kt[cur ^ 1] + inst * 2048 + w * 512);
            }
        }

        // ---- S^T = K Q^T (swapped operands; scores pre-scaled by 0.125)
        short8 kf[4][2];
#pragma unroll
        for (int n = 0; n < 4; n++) {
            int r = n * 16 + frow;
#pragma unroll
            for (int kk = 0; kk < 2; kk++)
                kf[n][kk] = *(const short8*)(Ks[cur] + r * 64 +
                                             (((kk << 2) + fk) ^ (r & 7)) * 8);
        }
        f32x4 st[4][2] = {};   // st[nk][mq]: rows kv, cols q
        __builtin_amdgcn_s_setprio(1);
#pragma unroll
        for (int nk = 0; nk < 4; nk++)
#pragma unroll
            for (int mq = 0; mq < 2; mq++)
#pragma unroll
                for (int kk = 0; kk < 2; kk++)
                    st[nk][mq] = __builtin_amdgcn_mfma_f32_16x16x32_bf16(
                        kf[nk][kk], qf[mq][kk], st[nk][mq], 0, 0, 0);
        __builtin_amdgcn_s_setprio(0);

        // ---- P = exp(S); lane holds P[kv = nk*16+fk*4+i][q = mq*16+frow]:
        //      kv-contiguous -> v_cvt_pk_bf16_f32 pairs + b64 LDS writes
#pragma unroll
        for (int mq = 0; mq < 2; mq++) {
            const int r = w * 32 + mq * 16 + frow;
            const int rb = r * 64, sw = (r & 7) << 3;
#pragma unroll
            for (int nk = 0; nk < 4; nk++) {
                float p0 = __expf(st[nk][mq][0]);
                float p1 = __expf(st[nk][mq][1]);
                float p2 = __expf(st[nk][mq][2]);
                float p3 = __expf(st[nk][mq][3]);
                lp[mq] += (p0 + p1) + (p2 + p3);
                *(uint2*)&Ps[rb + ((nk * 16 + fk * 4) ^ sw)] =
                    make_uint2(cvtpk(p0, p1), cvtpk(p2, p3));
            }
        }

        // ---- O += P V   (P rows written above by this same wave)
        short8 pa[2][2], vf[4][2];
#pragma unroll
        for (int m = 0; m < 2; m++) {
            int r = w * 32 + m * 16 + frow;
#pragma unroll
            for (int kk = 0; kk < 2; kk++)
                pa[m][kk] = *(const short8*)(Ps + r * 64 +
                                             (((kk << 2) + fk) ^ (r & 7)) * 8);
        }
#pragma unroll
        for (int n = 0; n < 4; n++) {
            int r = n * 16 + frow;
#pragma unroll
            for (int kk = 0; kk < 2; kk++)
                vf[n][kk] = *(const short8*)(Kt[cur] + r * 64 +
                                             (((kk << 2) + fk) ^ (r & 7)) * 8);
        }
        __builtin_amdgcn_s_setprio(1);
#pragma unroll
        for (int m = 0; m < 2; m++)
#pragma unroll
            for (int n = 0; n < 4; n++)
#pragma unroll
                for (int kk = 0; kk < 2; kk++)
                    o[m][n] = __builtin_amdgcn_mfma_f32_16x16x32_bf16(
                        pa[m][kk], vf[n][kk], o[m][n], 0, 0, 0);
        __builtin_amdgcn_s_setprio(0);

        __syncthreads();   // staging(t+1) drained; all waves done with buf cur
    }

    // ---- epilogue: finish row-sums, redistribute, write z = O*QUNSCALE/l
#pragma unroll
    for (int mq = 0; mq < 2; mq++) {
        lp[mq] += __shfl_xor(lp[mq], 16);
        lp[mq] += __shfl_xor(lp[mq], 32);
    }
#pragma unroll
    for (int m = 0; m < 2; m++)
#pragma unroll
        for (int i = 0; i < 4; i++) {
            const float lfull = __shfl(lp[m], fk * 4 + i);  // lane frow=fk*4+i
            const float rl = QUNSCALE / lfull;
            const size_t gr = (size_t)(b * 1024 + q0 + w * 32 + m * 16 + fk * 4 + i);
#pragma unroll
            for (int n = 0; n < 4; n++)
                zb[gr * 1024 + h * 64 + n * 16 + frow] = f2b(o[m][n][i] * rl);
        }
}

// ---------------------------------------------------------------------------
// Fused residual add + LayerNorm (ddof=1, eps on std). Vectorized (G13).
// ---------------------------------------------------------------------------
__device__ __forceinline__ float4 ld4(const float* p) { return *(const float4*)p; }
__device__ __forceinline__ float4 ld4(const u16* p) {
    ushort4 u = *(const ushort4*)p;
    return make_float4(b2f(u.x), b2f(u.y), b2f(u.z), b2f(u.w));
}
__device__ __forceinline__ void st4(float* p, float4 v) { *(float4*)p = v; }
__device__ __forceinline__ void st4(u16* p, float4 v) {
    *(uint2*)p = make_uint2(f2b2(v.x, v.y), f2b2(v.z, v.w));
}

template<typename TA, typename TB, typename TO>
__global__ __launch_bounds__(256) void add_ln(
    const TA* __restrict__ a, const TB* __restrict__ b,
    const float* __restrict__ alpha, const float* __restrict__ beta,
    TO* __restrict__ out)
{
    const int row = blockIdx.x;
    const int c = threadIdx.x * 4;
    float4 va = ld4(a + (size_t)row * DMODEL + c);
    float4 vb = ld4(b + (size_t)row * DMODEL + c);
    float v0 = va.x + vb.x, v1 = va.y + vb.y;
    float v2 = va.z + vb.z, v3 = va.w + vb.w;

    float sum = (v0 + v1) + (v2 + v3);
    float sq  = (v0 * v0 + v1 * v1) + (v2 * v2 + v3 * v3);
#pragma unroll
    for (int off = 32; off > 0; off >>= 1) {
        sum += __shfl_xor(sum, off);
        sq  += __shfl_xor(sq, off);
    }
    __shared__ float s1[4], s2[4];
    const int wid = threadIdx.x >> 6, lane = threadIdx.x & 63;
    if (lane == 0) { s1[wid] = sum; s2[wid] = sq; }
    __syncthreads();
    sum = (s1[0] + s1[1]) + (s1[2] + s1[3]);
    sq  = (s2[0] + s2[1]) + (s2[2] + s2[3]);

    const float mean = sum * (1.0f / 1024.0f);
    float var = (sq - 1024.0f * mean * mean) * (1.0f / 1023.0f);
    var = fmaxf(var, 0.0f);
    const float rdenom = 1.0f / (sqrtf(var) + 1e-6f);

    float4 al = *(const float4*)(alpha + c);
    float4 be = *(const float4*)(beta + c);
    float4 r;
    r.x = al.x * (v0 - mean) * rdenom + be.x;
    r.y = al.y * (v1 - mean) * rdenom + be.y;
    r.z = al.z * (v2 - mean) * rdenom + be.z;
    r.w = al.w * (v3 - mean) * rdenom + be.w;
    st4(out + (size_t)row * DMODEL + c, r);
}

// ---------------------------------------------------------------------------
extern "C" void kernel_launch(void* const* d_in, const int* in_sizes, int n_in,
                              void* d_out, int out_size, void* d_ws, size_t ws_size,
                              hipStream_t stream) {
    const float* x     = (const float*)d_in[0];
    const float* Wq    = (const float*)d_in[1];
    const float* bq    = (const float*)d_in[2];
    const float* Wo    = (const float*)d_in[3];
    const float* bo    = (const float*)d_in[4];
    const float* W1    = (const float*)d_in[5];
    const float* b1    = (const float*)d_in[6];
    const float* W2    = (const float*)d_in[7];
    const float* b2    = (const float*)d_in[8];
    const float* alpha = (const float*)d_in[9];
    const float* beta  = (const float*)d_in[10];

    // workspace layout (liveness-based reuse; 52 MB)
    char* base = (char*)d_ws;
    u16* Wqt = (u16*)base;                       //  0M: 2 MB
    u16* Wot = (u16*)(base + (2u  << 20));       //  2M: 2 MB
    u16* W1t = (u16*)(base + (4u  << 20));       //  4M: 4 MB
    u16* W2t = (u16*)(base + (8u  << 20));       //  8M: 4 MB
    u16* zb  = (u16*)(base + (12u << 20));       // 12M: 8 MB (attn out)
    u16* x1b = zb;                               //      reuse after Wo-gemm
    u16* qb  = (u16*)(base + (20u << 20));       // 20M: 8 MB (dead after attn)
    u16* g2  = qb;                               //      bf16 8 MB (FF2 out)
    u16* qT  = (u16*)(base + (28u << 20));       // 28M: 8 MB (dead after attn)
    u16* g   = qT;                               //      bf16 8 MB (Wo out)
    u16* xb  = (u16*)(base + (36u << 20));       // 36M: 8 MB (live thru LN1)
    u16* hb  = (u16*)(base + (36u << 20));       // 36M: 16 MB (xb dead pre-FF1)

    dim3 blk(256);
    dim3 wblk(64);

    // prep1: Wq transpose + x convert
    prep1<<<dim3(1280), blk, 0, stream>>>(Wq, Wqt, x, xb);

    // q = (x @ Wq + bq) * 8^-1/2, dual layout (qb row-major, qT transposed)
    gemm_w<false, true, true><<<dim3(1024), wblk, 0, stream>>>(
        xb, Wqt, bq, qb, qT, QSCALE, TOK, 1024, 1024);
    // attention -> zb + Wo/W1/W2 transposes (concurrent independent blocks)
    attn_prepw<<<dim3(1792), blk, 0, stream>>>(
        qb, qT, zb, Wo, W1, W2, Wot, W1t, W2t);
    // g = z @ Wo + bo  (bf16; writes over qT which is now dead)
    gemm_w<false, true, false><<<dim3(1024), wblk, 0, stream>>>(
        zb, Wot, bo, g, nullptr, 1.0f, TOK, 1024, 1024);
    // x1b = LN(xb + g)  (bf16 residual)
    add_ln<u16, u16, u16><<<dim3(TOK), blk, 0, stream>>>(xb, g, alpha, beta, x1b);
    // hb = relu(x1 @ W1 + b1)  (bf16)
    gemm_w<true, true, false><<<dim3(2048), wblk, 0, stream>>>(
        x1b, W1t, b1, hb, nullptr, 1.0f, TOK, 2048, 1024);
    // g2 = h @ W2 + b2  (bf16)
    gemm_w<false, true, false><<<dim3(1024), wblk, 0, stream>>>(
        hb, W2t, b2, g2, nullptr, 1.0f, TOK, 1024, 2048);
    // out = LN(x1 + g2)
    add_ln<u16, u16, float><<<dim3(TOK), blk, 0, stream>>>(
        x1b, g2, alpha, beta, (float*)d_out);
}